// Round 25
// baseline (305.048 us; speedup 1.0000x reference)
//
#include <hip/hip_runtime.h>
#include <hip/hip_bf16.h>

// ---------------------------------------------------------------------------
// DepthDeltaNetDecoderLayer: B=1, T=2048, D=1024, H=16, DK=DV=64, FF=4096
// Round 25: RoPE + L2-norm fused into the projection GEMM epilogue. N-tiles
// are 64-wide and head-aligned, and the rotate-half partner col^32 is in the
// same thread's register (acc[m][n^2][j]); the row L2-sum needs only 4
// __shfl_xor over the 16-lane group. Same f32 math as the standalone rope
// except the 64-term sum tree order (~2^-24 perturbation). rope_kernel launch
// and its 32 MB of HBM traffic removed.
// ---------------------------------------------------------------------------

#define T_SEQ 2048
#define D_MODEL 1024
#define NH 16
#define DK 64
#define DV 64
#define FF 4096
#define NQKV 4224   // X1: q(0) k(1024) v(2048) gate(3072) g(4096) b(4112) pad->4224
#define LP 72       // padded LDS stride (halfwords), 144B rows (16B-aligned)

typedef __bf16 bf16x8 __attribute__((ext_vector_type(8)));
typedef _Float16 fp16x8 __attribute__((ext_vector_type(8)));
typedef float  fx4    __attribute__((ext_vector_type(4)));

#if defined(__has_builtin)
#if __has_builtin(__builtin_amdgcn_global_load_lds)
#define HAVE_GLOAD_LDS 1
#endif
#endif

#ifdef HAVE_GLOAD_LDS
#define ASYNC_LDS16(dst, src)                                                   \
    __builtin_amdgcn_global_load_lds(                                           \
        (__attribute__((address_space(1))) void*)(src),                         \
        (__attribute__((address_space(3))) void*)(dst), 16, 0, 0)
#else
#define ASYNC_LDS16(dst, src) (*(int4*)(dst) = *(const int4*)(src))
#endif

// chunk swizzle within a 64B (32-halfword) tile row: involution, both sides.
__device__ __forceinline__ int swz_kk(int r, int ch) { return (ch ^ ((r >> 1) & 3)) * 8; }

// XCD-aware block remap (bijective when nwg % 8 == 0; all our grids qualify).
__device__ __forceinline__ void xcd_swizzle(int& bx, int& by) {
    int gx = gridDim.x, gy = gridDim.y;
    int id = blockIdx.y * gx + blockIdx.x;
    int cpx = (gx * gy) >> 3;
    int lin = (id & 7) * cpx + (id >> 3);
    bx = lin / gy;
    by = lin - bx * gy;
}

// ---------------------------------------------------------------- rope table
__global__ void rope_table_kernel(float2* __restrict__ cs) {
    int idx = blockIdx.x * 256 + threadIdx.x;
    int t = idx >> 5, i = idx & 31;
    float freq = (float)t * powf(10000.f, -(float)i / 32.f);
    cs[idx] = make_float2(cosf(freq), sinf(freq));
}

// --------------------------------------- row rmsnorm -> fp16
__global__ __launch_bounds__(256) void rmsnorm_fp16_kernel(
    const float* __restrict__ in, const float* __restrict__ w,
    _Float16* __restrict__ out) {
    int t = blockIdx.x;
    int d = threadIdx.x * 4;
    const float4 v = *(const float4*)(in + (size_t)t * D_MODEL + d);
    float ss = v.x * v.x + v.y * v.y + v.z * v.z + v.w * v.w;
#pragma unroll
    for (int m = 32; m; m >>= 1) ss += __shfl_xor(ss, m, 64);
    __shared__ float wsum[4];
    if ((threadIdx.x & 63) == 0) wsum[threadIdx.x >> 6] = ss;
    __syncthreads();
    float tot = wsum[0] + wsum[1] + wsum[2] + wsum[3];
    float sc = rsqrtf(tot * (1.f / 1024.f) + 1e-6f);
    const float4 wv = *(const float4*)(w + d);
    _Float16* op = out + (size_t)t * D_MODEL + d;
    op[0] = (_Float16)(v.x * sc * wv.x);
    op[1] = (_Float16)(v.y * sc * wv.y);
    op[2] = (_Float16)(v.z * sc * wv.z);
    op[3] = (_Float16)(v.w * sc * wv.w);
}

// -------------------------- row rmsnorm (f32 in) -> bf16
__global__ __launch_bounds__(256) void rmsnorm_bf16_kernel(
    const float* __restrict__ in, const float* __restrict__ w,
    __hip_bfloat16* __restrict__ out) {
    int t = blockIdx.x;
    int d = threadIdx.x * 4;
    const float4 h4 = *(const float4*)(in + (size_t)t * D_MODEL + d);
    float ss = h4.x * h4.x + h4.y * h4.y + h4.z * h4.z + h4.w * h4.w;
#pragma unroll
    for (int m = 32; m; m >>= 1) ss += __shfl_xor(ss, m, 64);
    __shared__ float wsum[4];
    if ((threadIdx.x & 63) == 0) wsum[threadIdx.x >> 6] = ss;
    __syncthreads();
    float tot = wsum[0] + wsum[1] + wsum[2] + wsum[3];
    float sc = rsqrtf(tot * (1.f / 1024.f) + 1e-6f);
    const float4 wv = *(const float4*)(w + d);
    __hip_bfloat16* op = out + (size_t)t * D_MODEL + d;
    op[0] = __float2bfloat16(h4.x * sc * wv.x);
    op[1] = __float2bfloat16(h4.y * sc * wv.y);
    op[2] = __float2bfloat16(h4.z * sc * wv.z);
    op[3] = __float2bfloat16(h4.w * sc * wv.w);
}

// ------------------- batched W (KxN f32) -> Wt (Npad x K fp16), z selects src
__global__ void transpose_fp16_x6_kernel(const float* __restrict__ q,
                                         const float* __restrict__ k,
                                         const float* __restrict__ v,
                                         const float* __restrict__ g,
                                         const float* __restrict__ gw,
                                         const float* __restrict__ bw,
                                         _Float16* __restrict__ Wt) {
    const int z = blockIdx.z;
    const float* W;
    int N, Npad;
    size_t ooff;
    switch (z) {
        case 0: W = q;  N = 1024; Npad = 1024; ooff = 0;               break;
        case 1: W = k;  N = 1024; Npad = 1024; ooff = 1024u * 1024u;   break;
        case 2: W = v;  N = 1024; Npad = 1024; ooff = 2048u * 1024u;   break;
        case 3: W = g;  N = 1024; Npad = 1024; ooff = 3072u * 1024u;   break;
        case 4: W = gw; N = 16;   Npad = 16;   ooff = 4096u * 1024u;   break;
        default: W = bw; N = 16;  Npad = 112;  ooff = 4112u * 1024u;   break;
    }
    __shared__ float tile[32][33];
    int k0 = blockIdx.x * 32, n0 = blockIdx.y * 32;
    if (n0 >= Npad) return;
    int tx = threadIdx.x, ty = threadIdx.y;   // (32,8)
#pragma unroll
    for (int i = 0; i < 32; i += 8) {
        int n = n0 + tx;
        tile[ty + i][tx] = (n < N) ? W[(size_t)(k0 + ty + i) * N + n] : 0.f;
    }
    __syncthreads();
#pragma unroll
    for (int i = 0; i < 32; i += 8) {
        int n = n0 + ty + i;
        if (n < Npad) Wt[ooff + (size_t)n * 1024 + k0 + tx] = (_Float16)tile[tx][ty + i];
    }
}

// ------------------------------------------- W (KxN f32) -> Wt (Npad x K bf16)
__global__ void transpose_bf16_kernel(const float* __restrict__ W,
                                      __hip_bfloat16* __restrict__ Wt,
                                      int K, int N, int Npad) {
    __shared__ float tile[32][33];
    int k0 = blockIdx.x * 32, n0 = blockIdx.y * 32;
    int tx = threadIdx.x, ty = threadIdx.y;   // (32,8)
#pragma unroll
    for (int i = 0; i < 32; i += 8) {
        int n = n0 + tx;
        tile[ty + i][tx] = (n < N) ? W[(size_t)(k0 + ty + i) * N + n] : 0.f;
    }
    __syncthreads();
#pragma unroll
    for (int i = 0; i < 32; i += 8) {
        int n = n0 + ty + i;
        if (n < Npad) Wt[(size_t)n * K + k0 + tx] = __float2bfloat16(tile[tx][ty + i]);
    }
}

// ---------- batched gate/up W (1024x4096 f32) -> Wt (4096 x 1024 bf16), z=0/1
__global__ void transpose_bf16_gu_kernel(const float* __restrict__ gate,
                                         const float* __restrict__ up,
                                         __hip_bfloat16* __restrict__ Wt) {
    const float* W = blockIdx.z ? up : gate;
    __hip_bfloat16* out = Wt + (size_t)blockIdx.z * 4096u * 1024u;
    __shared__ float tile[32][33];
    int k0 = blockIdx.x * 32, n0 = blockIdx.y * 32;
    int tx = threadIdx.x, ty = threadIdx.y;   // (32,8)
#pragma unroll
    for (int i = 0; i < 32; i += 8)
        tile[ty + i][tx] = W[(size_t)(k0 + ty + i) * 4096 + n0 + tx];
    __syncthreads();
#pragma unroll
    for (int i = 0; i < 32; i += 8)
        out[(size_t)(n0 + ty + i) * 1024 + k0 + tx] = __float2bfloat16(tile[tx][ty + i]);
}

// ----- fp16 single-product GEMM, 128x64 tile, f32 out; RoPE+L2norm fused for
// ----- q/k tiles (bn0 < 2048). N-tiles are head-aligned; partner col^32 is
// ----- acc[m][n^2][j] in the same thread; row L2-sum via 4 shfl_xor (16-lane).
__global__ __launch_bounds__(256) void gemm_bt_f16(
    const _Float16* __restrict__ A, const _Float16* __restrict__ Bt,
    float* __restrict__ Cout, const float2* __restrict__ cs,
    int M, int K, int ldc) {
    __shared__ short sA[2][128 * 32];
    __shared__ short sB[2][64 * 32];
    const int tid = threadIdx.x;
    const int w = tid >> 6, lane = tid & 63;
    int bx, by;
    xcd_swizzle(bx, by);
    const int bn0 = bx * 64, bm0 = by * 128;
    const int ko = ((lane >> 4) ^ (((lane & 15) >> 1) & 3)) * 8;

    fx4 acc[2][4];
#pragma unroll
    for (int m = 0; m < 2; ++m)
#pragma unroll
        for (int n = 0; n < 4; ++n) acc[m][n] = {0.f, 0.f, 0.f, 0.f};

#pragma unroll
    for (int i = 0; i < 2; ++i) {
        int c = i * 256 + tid;
        int r = c >> 2, kk = swz_kk(r, c & 3);
        ASYNC_LDS16(&sA[0][c * 8], A + (size_t)(bm0 + r) * K + kk);
    }
    {
        int r = tid >> 2, kk = swz_kk(r, tid & 3);
        ASYNC_LDS16(&sB[0][tid * 8], Bt + (size_t)(bn0 + r) * K + kk);
    }
    __syncthreads();

    const int NT = K >> 5;
    int cur = 0;
    for (int t = 0; t < NT; ++t) {
        if (t + 1 < NT) {
            int k0 = (t + 1) << 5;
#pragma unroll
            for (int i = 0; i < 2; ++i) {
                int c = i * 256 + tid;
                int r = c >> 2, kk = swz_kk(r, c & 3);
                ASYNC_LDS16(&sA[cur ^ 1][c * 8], A + (size_t)(bm0 + r) * K + k0 + kk);
            }
            int r = tid >> 2, kk = swz_kk(r, tid & 3);
            ASYNC_LDS16(&sB[cur ^ 1][tid * 8], Bt + (size_t)(bn0 + r) * K + k0 + kk);
        }
        fp16x8 af[2], bfv[4];
#pragma unroll
        for (int m = 0; m < 2; ++m)
            af[m] = *(const fp16x8*)(&sA[cur][(w * 32 + m * 16 + (lane & 15)) * 32 + ko]);
#pragma unroll
        for (int n = 0; n < 4; ++n)
            bfv[n] = *(const fp16x8*)(&sB[cur][(n * 16 + (lane & 15)) * 32 + ko]);
#pragma unroll
        for (int m = 0; m < 2; ++m)
#pragma unroll
            for (int n = 0; n < 4; ++n)
                acc[m][n] = __builtin_amdgcn_mfma_f32_16x16x32_f16(af[m], bfv[n], acc[m][n], 0, 0, 0);
        __syncthreads();
        cur ^= 1;
    }

    const bool do_rope = (bn0 < 2048);
#pragma unroll
    for (int m = 0; m < 2; ++m) {
        int row = bm0 + w * 32 + m * 16 + (lane >> 4) * 4;
        if (do_rope) {
#pragma unroll
            for (int j = 0; j < 4; ++j) {
                int t = row + j;
                float2 c0 = cs[t * 32 + (lane & 15)];
                float2 c1 = cs[t * 32 + 16 + (lane & 15)];
                float y[4];
                float ss = 0.f;
#pragma unroll
                for (int n = 0; n < 4; ++n) {
                    float x = acc[m][n][j];
                    float xo = acc[m][n ^ 2][j];
                    float r = (n < 2) ? -xo : xo;
                    float2 c = (n & 1) ? c1 : c0;
                    y[n] = x * c.x + r * c.y;
                    ss += y[n] * y[n];
                }
#pragma unroll
                for (int mk = 1; mk < 16; mk <<= 1) ss += __shfl_xor(ss, mk, 64);
                float sc = rsqrtf(ss + 1e-12f);
#pragma unroll
                for (int n = 0; n < 4; ++n)
                    Cout[(size_t)t * ldc + bn0 + n * 16 + (lane & 15)] = y[n] * sc;
            }
        } else {
#pragma unroll
            for (int n = 0; n < 4; ++n) {
                int col = bn0 + n * 16 + (lane & 15);
#pragma unroll
                for (int j = 0; j < 4; ++j)
                    Cout[(size_t)(row + j) * ldc + col] = acc[m][n][j];
            }
        }
    }
}

// ------------------- fused gate/up GEMM + silu·mul epilogue, 128x64 tile
__global__ __launch_bounds__(256) void gemm_gateup(
    const __hip_bfloat16* __restrict__ A, const __hip_bfloat16* __restrict__ Btg,
    const __hip_bfloat16* __restrict__ Btu, __hip_bfloat16* __restrict__ Mout,
    int M, int K) {
    __shared__ short sA[2][128 * 32];
    __shared__ short sBg[2][64 * 32];
    __shared__ short sBu[2][64 * 32];
    const int tid = threadIdx.x;
    const int w = tid >> 6, lane = tid & 63;
    int bx, by;
    xcd_swizzle(bx, by);
    const int bn0 = bx * 64, bm0 = by * 128;
    const int ko = ((lane >> 4) ^ (((lane & 15) >> 1) & 3)) * 8;

    fx4 accg[2][4], accu[2][4];
#pragma unroll
    for (int m = 0; m < 2; ++m)
#pragma unroll
        for (int n = 0; n < 4; ++n) {
            accg[m][n] = {0.f, 0.f, 0.f, 0.f};
            accu[m][n] = {0.f, 0.f, 0.f, 0.f};
        }

#pragma unroll
    for (int i = 0; i < 2; ++i) {
        int c = i * 256 + tid;
        int r = c >> 2, kk = swz_kk(r, c & 3);
        ASYNC_LDS16(&sA[0][c * 8], A + (size_t)(bm0 + r) * K + kk);
    }
    {
        int r = tid >> 2, kk = swz_kk(r, tid & 3);
        ASYNC_LDS16(&sBg[0][tid * 8], Btg + (size_t)(bn0 + r) * K + kk);
        ASYNC_LDS16(&sBu[0][tid * 8], Btu + (size_t)(bn0 + r) * K + kk);
    }
    __syncthreads();

    const int NT = K >> 5;
    int cur = 0;
    for (int t = 0; t < NT; ++t) {
        if (t + 1 < NT) {
            int k0 = (t + 1) << 5;
#pragma unroll
            for (int i = 0; i < 2; ++i) {
                int c = i * 256 + tid;
                int r = c >> 2, kk = swz_kk(r, c & 3);
                ASYNC_LDS16(&sA[cur ^ 1][c * 8], A + (size_t)(bm0 + r) * K + k0 + kk);
            }
            int r = tid >> 2, kk = swz_kk(r, tid & 3);
            ASYNC_LDS16(&sBg[cur ^ 1][tid * 8], Btg + (size_t)(bn0 + r) * K + k0 + kk);
            ASYNC_LDS16(&sBu[cur ^ 1][tid * 8], Btu + (size_t)(bn0 + r) * K + k0 + kk);
        }
        bf16x8 af[2], bg[4], bu[4];
#pragma unroll
        for (int m = 0; m < 2; ++m)
            af[m] = *(const bf16x8*)(&sA[cur][(w * 32 + m * 16 + (lane & 15)) * 32 + ko]);
#pragma unroll
        for (int n = 0; n < 4; ++n) {
            int off = (n * 16 + (lane & 15)) * 32 + ko;
            bg[n] = *(const bf16x8*)(&sBg[cur][off]);
            bu[n] = *(const bf16x8*)(&sBu[cur][off]);
        }
#pragma unroll
        for (int m = 0; m < 2; ++m)
#pragma unroll
            for (int n = 0; n < 4; ++n) {
                accg[m][n] = __builtin_amdgcn_mfma_f32_16x16x32_bf16(af[m], bg[n], accg[m][n], 0, 0, 0);
                accu[m][n] = __builtin_amdgcn_mfma_f32_16x16x32_bf16(af[m], bu[n], accu[m][n], 0, 0, 0);
            }
        __syncthreads();
        cur ^= 1;
    }
#pragma unroll
    for (int m = 0; m < 2; ++m) {
        int row = bm0 + w * 32 + m * 16 + (lane >> 4) * 4;
#pragma unroll
        for (int n = 0; n < 4; ++n) {
            int col = bn0 + n * 16 + (lane & 15);
#pragma unroll
            for (int j = 0; j < 4; ++j) {
                float g = accg[m][n][j];
                float u = accu[m][n][j];
                float sg = g / (1.f + expf(-g));
                Mout[(size_t)(row + j) * 4096 + col] = __float2bfloat16(u * sg);
            }
        }
    }
}

// ----------------------------------------- GEMM, 64x64 tile (small-N shapes)
template <bool OUT_BF16>
__global__ __launch_bounds__(256, 8) void gemm_bt_n64(
    const __hip_bfloat16* __restrict__ A, const __hip_bfloat16* __restrict__ Bt,
    void* __restrict__ Cout, const float* __restrict__ Add, int M, int N, int K) {
    __shared__ short sA[2][64 * 32];
    __shared__ short sB[2][64 * 32];
    const int tid = threadIdx.x;
    const int w = tid >> 6, lane = tid & 63;
    int bx, by;
    xcd_swizzle(bx, by);
    const int bn0 = bx * 64, bm0 = by * 64;
    const int ko = ((lane >> 4) ^ (((lane & 15) >> 1) & 3)) * 8;
    const int rs = tid >> 2, cs = tid & 3;

    fx4 acc[4];
#pragma unroll
    for (int n = 0; n < 4; ++n) acc[n] = {0.f, 0.f, 0.f, 0.f};

    {
        int kk = swz_kk(rs, cs);
        ASYNC_LDS16(&sA[0][tid * 8], A + (size_t)(bm0 + rs) * K + kk);
        ASYNC_LDS16(&sB[0][tid * 8], Bt + (size_t)(bn0 + rs) * K + kk);
    }
    __syncthreads();

    const int NT = K >> 5;
    int cur = 0;
    for (int t = 0; t < NT; ++t) {
        if (t + 1 < NT) {
            int k0 = (t + 1) << 5;
            int kk = swz_kk(rs, cs);
            ASYNC_LDS16(&sA[cur ^ 1][tid * 8], A + (size_t)(bm0 + rs) * K + k0 + kk);
            ASYNC_LDS16(&sB[cur ^ 1][tid * 8], Bt + (size_t)(bn0 + rs) * K + k0 + kk);
        }
        bf16x8 af = *(const bf16x8*)(&sA[cur][(w * 16 + (lane & 15)) * 32 + ko]);
#pragma unroll
        for (int n = 0; n < 4; ++n) {
            bf16x8 bf = *(const bf16x8*)(&sB[cur][(n * 16 + (lane & 15)) * 32 + ko]);
            acc[n] = __builtin_amdgcn_mfma_f32_16x16x32_bf16(af, bf, acc[n], 0, 0, 0);
        }
        __syncthreads();
        cur ^= 1;
    }
    {
        int row = bm0 + w * 16 + (lane >> 4) * 4;
#pragma unroll
        for (int n = 0; n < 4; ++n) {
            int col = bn0 + n * 16 + (lane & 15);
#pragma unroll
            for (int j = 0; j < 4; ++j) {
                float val = acc[n][j];
                if (Add) val += Add[(size_t)(row + j) * N + col];
                if (OUT_BF16)
                    ((__hip_bfloat16*)Cout)[(size_t)(row + j) * N + col] = __float2bfloat16(val);
                else
                    ((float*)Cout)[(size_t)(row + j) * N + col] = val;
            }
        }
    }
}

// ===================== chunked delta-rule: shared helpers =====================
// single-product fp16 64x64x64 matmul: C[ar][br] += sum_k A[ar][k] B[br][k]
__device__ __forceinline__ void mm64_f16(const _Float16* A, const _Float16* B,
                                         int w, int lane, fx4 acc[4]) {
#pragma unroll
    for (int k0 = 0; k0 < 64; k0 += 32) {
        int ao = (w * 16 + (lane & 15)) * LP + k0 + ((lane >> 4) * 8);
        fp16x8 a = *(const fp16x8*)(A + ao);
#pragma unroll
        for (int n = 0; n < 4; ++n) {
            int bo = (n * 16 + (lane & 15)) * LP + k0 + ((lane >> 4) * 8);
            fp16x8 b = *(const fp16x8*)(B + bo);
            acc[n] = __builtin_amdgcn_mfma_f32_16x16x32_f16(a, b, acc[n], 0, 0, 0);
        }
    }
}

// ------------------------------------------------ phase A1 (blocked solve, v3)
__global__ __launch_bounds__(256) void phaseA1_kernel(const float* __restrict__ X1,
                                                      _Float16* __restrict__ UvWT) {
    const int h = blockIdx.x & 15, c = blockIdx.x >> 4;
    const int tid = threadIdx.x, w = tid >> 6, lane = tid & 63;
    const int t0 = c * 64;

    __shared__ __align__(16) float XT[128 * 66];   // overlay: first 9216B = K staging (fp16)
    _Float16* b1f = (_Float16*)XT;
    __shared__ float sMd[4][16 * 17];
    __shared__ _Float16 mbf[6][512];
    __shared__ float sLa[64], sB[64], sL[65], sGp[64];

    const float* k_g = X1 + (size_t)t0 * NQKV + 1024 + h * 64;
    const float* v_g = X1 + (size_t)t0 * NQKV + 2048 + h * 64;

    if (tid < 64) {
        float ga = X1[(size_t)(t0 + tid) * NQKV + 4096 + h];
        float gb = X1[(size_t)(t0 + tid) * NQKV + 4112 + h];
        float z = -ga;
        sLa[tid] = -(fmaxf(z, 0.f) + log1pf(expf(-fabsf(z))));
        sB[tid] = 1.f / (1.f + expf(-gb));
    }
    __syncthreads();
    if (tid < 64) {
        float v = sLa[tid];
#pragma unroll
        for (int off = 1; off < 64; off <<= 1) {
            float u = __shfl_up(v, off, 64);
            if (tid >= off) v += u;
        }
        sL[tid + 1] = v;
        if (tid == 0) sL[0] = 0.f;
    }
    __syncthreads();
    if (tid < 64) sGp[tid] = expf(sL[tid]);
    for (int idx = tid; idx < 3072; idx += 256) ((_Float16*)mbf)[idx] = (_Float16)0.f;
    for (int idx = tid; idx < 4096; idx += 256) {
        int r = idx >> 6, cc = idx & 63;
        b1f[r * LP + cc] = (_Float16)k_g[(size_t)r * NQKV + cc];
    }
    __syncthreads();

    {
        const int r0 = w * 16;
        fx4 acc[4];
#pragma unroll
        for (int n = 0; n < 4; ++n) acc[n] = {0.f, 0.f, 0.f, 0.f};
#pragma unroll
        for (int k0 = 0; k0 < 64; k0 += 32) {
            int ao = (r0 + (lane & 15)) * LP + k0 + ((lane >> 4) * 8);
            fp16x8 a = *(const fp16x8*)(b1f + ao);
#pragma unroll
            for (int n = 0; n < 4; ++n) {
                int bo = (n * 16 + (lane & 15)) * LP + k0 + ((lane >> 4) * 8);
                fp16x8 b = *(const fp16x8*)(b1f + bo);
                acc[n] = __builtin_amdgcn_mfma_f32_16x16x32_f16(a, b, acc[n], 0, 0, 0);
            }
        }
#pragma unroll
        for (int n = 0; n < 4; ++n)
#pragma unroll
            for (int jj = 0; jj < 4; ++jj) {
                int t = r0 + (lane >> 4) * 4 + jj, s = n * 16 + (lane & 15);
                if (s < t) {
                    float mv = sB[t] * expf(sL[t] - sL[s + 1]) * acc[n][jj];
                    int J = s >> 4, tl = t - r0, sl = s & 15;
                    if (J == w) {
                        sMd[w][tl * 17 + sl] = mv;
                    } else {
                        int blk = ((w * (w - 1)) >> 1) + J;
                        mbf[blk][tl * 32 + sl] = (_Float16)mv;
                    }
                }
            }
    }
    __syncthreads();

#pragma unroll 1
    for (int I = 0; I < 4; ++I) {
        if (I > 0) {
            fx4 acc2[2];
            acc2[0] = {0.f, 0.f, 0.f, 0.f};
            acc2[1] = {0.f, 0.f, 0.f, 0.f};
#pragma unroll
            for (int g = 0; g < 2; ++g) {
                const int jb = (w * 2 + g) * 16;
                for (int J = 0; J < I; ++J) {
                    int blk = ((I * (I - 1)) >> 1) + J;
                    fp16x8 a = *(const fp16x8*)((const _Float16*)&mbf[blk][0] +
                                                (lane & 15) * 32 + (lane >> 4) * 8);
                    fp16x8 b;
                    int kabs = J * 16 + ((lane >> 4) * 8);
                    if (kabs < I * 16) {
                        const float* xp = &XT[(jb + (lane & 15)) * 66 + kabs];
#pragma unroll
                        for (int e = 0; e < 8; ++e) b[e] = (_Float16)xp[e];
                    } else {
#pragma unroll
                        for (int e = 0; e < 8; ++e) b[e] = (_Float16)0.f;
                    }
                    acc2[g] = __builtin_amdgcn_mfma_f32_16x16x32_f16(a, b, acc2[g], 0, 0, 0);
                }
            }
#pragma unroll
            for (int g = 0; g < 2; ++g) {
                const int jb = (w * 2 + g) * 16;
#pragma unroll
                for (int jj = 0; jj < 4; ++jj) {
                    int j = jb + (lane & 15);
                    int t = I * 16 + (lane >> 4) * 4 + jj;
                    XT[j * 66 + t] = acc2[g][jj];
                }
            }
        }
        __syncthreads();
        if (tid < 128) {
            const int j = tid;
            float xs[16];
#pragma unroll
            for (int tl = 0; tl < 16; ++tl) {
                const int t = I * 16 + tl;
                float base = (j < 64) ? v_g[(size_t)t * NQKV + j]
                                      : k_g[(size_t)t * NQKV + (j - 64)] * sGp[t];
                float r = sB[t] * base;
                if (I > 0) r -= XT[j * 66 + t];
#pragma unroll
                for (int sl = 0; sl < tl; ++sl)
                    r = fmaf(-sMd[I][tl * 17 + sl], xs[sl], r);
                xs[tl] = r;
                XT[j * 66 + t] = r;
            }
        }
        __syncthreads();
    }

    size_t obase = (size_t)(h * 32 + c) * 8192;
    for (int idx = tid; idx < 8192; idx += 256) {
        int t = idx >> 7, j = idx & 127;
        UvWT[obase + idx] = (_Float16)XT[j * 66 + t];
    }
}

// ------------------------------------------------ phase A2 (matmuls, fp16)
__global__ __launch_bounds__(256) void phaseA2_kernel(float* __restrict__ X1,
                                                      const _Float16* __restrict__ UvWT,
                                                      _Float16* __restrict__ AcBuf,
                                                      float* __restrict__ BcBuf) {
    const int h = blockIdx.x & 15, c = blockIdx.x >> 4;
    const int tid = threadIdx.x, w = tid >> 6, lane = tid & 63;
    const int t0 = c * 64;

    __shared__ _Float16 b1f[64 * LP], b2f[64 * LP], b3f[64 * LP], b4f[64 * LP];
    __shared__ float sLa[64], sL[65], sGp[64], sRc[64];

    const float* q_g = X1 + (size_t)t0 * NQKV + h * 64;
    const float* k_g = q_g + 1024;

    if (tid < 64) {
        float ga = X1[(size_t)(t0 + tid) * NQKV + 4096 + h];
        float z = -ga;
        sLa[tid] = -(fmaxf(z, 0.f) + log1pf(expf(-fabsf(z))));
    }
    __syncthreads();
    if (tid < 64) {
        float v = sLa[tid];
#pragma unroll
        for (int off = 1; off < 64; off <<= 1) {
            float u = __shfl_up(v, off, 64);
            if (tid >= off) v += u;
        }
        sL[tid + 1] = v;
        if (tid == 0) sL[0] = 0.f;
    }
    __syncthreads();
    if (tid < 64) {
        sGp[tid] = expf(sL[tid]);
        sRc[tid] = expf(sL[64] - sL[tid + 1]);
    }
    for (int idx = tid; idx < 4096; idx += 256) {
        int r = idx >> 6, cc = idx & 63;
        b2f[r * LP + cc] = (_Float16)q_g[(size_t)r * NQKV + cc];
        b1f[r * LP + cc] = (_Float16)k_g[(size_t)r * NQKV + cc];
    }
    const _Float16* uv = UvWT + (size_t)(h * 32 + c) * 8192;
    for (int idx = tid; idx < 8192; idx += 256) {
        int t = idx >> 7, row = idx & 127;
        _Float16* d = (row < 64) ? b3f : b4f;
        d[(row & 63) * LP + t] = uv[idx];
    }
    __syncthreads();

    fx4 pacc[4];
#pragma unroll
    for (int n = 0; n < 4; ++n) pacc[n] = {0.f, 0.f, 0.f, 0.f};
    mm64_f16(b2f, b1f, w, lane, pacc);
    __syncthreads();
#pragma unroll
    for (int n = 0; n < 4; ++n)
#pragma unroll
        for (int jj = 0; jj < 4; ++jj) {
            int t = w * 16 + (lane >> 4) * 4 + jj, s = n * 16 + (lane & 15);
            float pv = (s < t) ? expf(sL[t] - sL[s + 1]) * pacc[n][jj] : 0.f;
            b2f[t * LP + s] = (_Float16)pv;
        }
    __syncthreads();

    {
        fx4 acc[4];
#pragma unroll
        for (int n = 0; n < 4; ++n) acc[n] = {0.f, 0.f, 0.f, 0.f};
        mm64_f16(b2f, b3f, w, lane, acc);
        float* og = X1 + (size_t)t0 * NQKV + 1024 + h * 64;
#pragma unroll
        for (int n = 0; n < 4; ++n)
#pragma unroll
            for (int jj = 0; jj < 4; ++jj) {
                int t = w * 16 + (lane >> 4) * 4 + jj, s = n * 16 + (lane & 15);
                og[(size_t)t * NQKV + s] = acc[n][jj];
            }
    }
    {
        fx4 acc[4];
#pragma unroll
        for (int n = 0; n < 4; ++n) acc[n] = {0.f, 0.f, 0.f, 0.f};
        mm64_f16(b2f, b4f, w, lane, acc);
        float* qg = X1 + (size_t)t0 * NQKV + h * 64;
#pragma unroll
        for (int n = 0; n < 4; ++n)
#pragma unroll
            for (int jj = 0; jj < 4; ++jj) {
                int t = w * 16 + (lane >> 4) * 4 + jj, s = n * 16 + (lane & 15);
                float qv = qg[(size_t)t * NQKV + s];
                qg[(size_t)t * NQKV + s] = sGp[t] * qv - acc[n][jj];
            }
    }
    __syncthreads();
    for (int idx = tid; idx < 4096; idx += 256) {
        int s = idx >> 6, i = idx & 63;
        float kv = (float)b1f[s * LP + i];
        b2f[i * LP + s] = (_Float16)(sRc[s] * kv);
    }
    __syncthreads();

    {
        fx4 acc[4];
#pragma unroll
        for (int n = 0; n < 4; ++n) acc[n] = {0.f, 0.f, 0.f, 0.f};
        mm64_f16(b2f, b4f, w, lane, acc);
        float gend = expf(sL[64]);
        size_t abase = (size_t)(h * 32 + c) * 4096;
#pragma unroll
        for (int n = 0; n < 4; ++n)
#pragma unroll
            for (int jj = 0; jj < 4; ++jj) {
                int i = w * 16 + (lane >> 4) * 4 + jj, jd = n * 16 + (lane & 15);
                float av = ((i == jd) ? gend : 0.f) - acc[n][jj];
                AcBuf[abase + i * 64 + jd] = (_Float16)av;
            }
    }
    {
        fx4 acc[4];
#pragma unroll
        for (int n = 0; n < 4; ++n) acc[n] = {0.f, 0.f, 0.f, 0.f};
        mm64_f16(b3f, b2f, w, lane, acc);
        size_t bbase = (size_t)(h * 32 + c) * 4096;
#pragma unroll
        for (int n = 0; n < 4; ++n)
#pragma unroll
            for (int jj = 0; jj < 4; ++jj) {
                int jv = w * 16 + (lane >> 4) * 4 + jj, i = n * 16 + (lane & 15);
                BcBuf[bbase + jv * 64 + i] = acc[n][jj];
            }
    }
}

// --------------------------------------------------- phase B (state recurrence)
__global__ __launch_bounds__(256) void phaseB_kernel(const _Float16* __restrict__ AcBuf,
                                                     const float* __restrict__ BcBuf,
                                                     float* __restrict__ X1) {
    const int h = blockIdx.x;
    const int tid = threadIdx.x, w = tid >> 6, lane = tid & 63;
    const int lr = (lane >> 4) * 4;
    const int lc = lane & 15;
    __shared__ _Float16 sAc[2][4096];
    __shared__ float sST[64 * 68];

    const size_t hc0 = (size_t)h * 32;
    {
        const char* src = (const char*)AcBuf + hc0 * 8192;
        char* dst = (char*)&sAc[0][0];
        int off = tid * 16;
        ASYNC_LDS16(dst + off, src + off);
        ASYNC_LDS16(dst + off + 4096, src + off + 4096);
    }
    fx4 acc[4];
#pragma unroll
    for (int n = 0; n < 4; ++n) acc[n] = {0.f, 0.f, 0.f, 0.f};
    float bcur[16];
    {
        const float* bg = BcBuf + hc0 * 4096;
#pragma unroll
        for (int n = 0; n < 4; ++n)
#pragma unroll
            for (int jj = 0; jj < 4; ++jj)
                bcur[n * 4 + jj] = bg[(w * 16 + lr + jj) * 64 + n * 16 + lc];
    }

#pragma unroll 1
    for (int c = 0; c < 32; ++c) {
        __syncthreads();
        {
            int cn = (c < 31) ? c + 1 : 31;
            const char* src = (const char*)AcBuf + (hc0 + cn) * 8192;
            char* dst = (char*)&sAc[(c + 1) & 1][0];
            int off = tid * 16;
            ASYNC_LDS16(dst + off, src + off);
            ASYNC_LDS16(dst + off + 4096, src + off + 4096);
        }
        float bnext[16];
        {
            int cn = (c < 31) ? c + 1 : 31;
            const float* bg = BcBuf + (hc0 + cn) * 4096;
#pragma unroll
            for (int n = 0; n < 4; ++n)
#pragma unroll
                for (int jj = 0; jj < 4; ++jj)
                    bnext[n * 4 + jj] = bg[(w * 16 + lr + jj) * 64 + n * 16 + lc];
        }
        float* stg = X1 + (size_t)(c * 64) * NQKV + 2048 + h * 64;
#pragma unroll
        for (int n = 0; n < 4; ++n)
#pragma unroll
            for (int jj = 0; jj < 4; ++jj) {
                int r = w * 16 + lr + jj, i = n * 16 + lc;
                stg[(size_t)r * NQKV + i] = acc[n][jj];
                sST[r * 68 + i] = acc[n][jj];
            }
        const _Float16* bufc = &sAc[c & 1][0];
        fx4 nacc[4];
#pragma unroll
        for (int n = 0; n < 4; ++n)
            nacc[n] = {bcur[n * 4 + 0], bcur[n * 4 + 1], bcur[n * 4 + 2], bcur[n * 4 + 3]};
#pragma unroll
        for (int k0 = 0; k0 < 2; ++k0) {
            const float* ap = sST + (w * 16 + lc) * 68 + k0 * 32 + (lane >> 4) * 8;
            float4 f0 = *(const float4*)ap;
            float4 f1 = *(const float4*)(ap + 4);
            float fv[8] = {f0.x, f0.y, f0.z, f0.w, f1.x, f1.y, f1.z, f1.w};
            fp16x8 af_;
#pragma unroll
            for (int e = 0; e < 8; ++e) af_[e] = (_Float16)fv[e];
#pragma unroll
            for (int n = 0; n < 4; ++n) {
                int ro = (n * 16 + lc) * 64 + k0 * 32 + (lane >> 4) * 8;
                fp16x8 b_ = *(const fp16x8*)(bufc + ro);
                nacc[n] = __builtin_amdgcn_mfma_f32_16x16x32_f16(af_, b_, nacc[n], 0, 0, 0);
            }
        }
#pragma unroll
        for (int n = 0; n < 4; ++n) acc[n] = nacc[n];
#pragma unroll
        for (int e = 0; e < 16; ++e) bcur[e] = bnext[e];
    }
}

// --------------------------------------------- phase C (outputs + epilogue)
__global__ __launch_bounds__(256) void phaseC_kernel(const float* __restrict__ X1,
                                                     const float* __restrict__ onw,
                                                     __hip_bfloat16* __restrict__ attn_bf) {
    const int h = blockIdx.x & 15, c = blockIdx.x >> 4;
    const int tid = threadIdx.x, w = tid >> 6, lane = tid & 63;
    const int t0 = c * 64;
    __shared__ _Float16 qf[64 * LP], sf[64 * LP];
    __shared__ float sO[4096];
    __shared__ float part[64][4];
    const float* qe = X1 + (size_t)t0 * NQKV + h * 64;
    const float* stg = X1 + (size_t)t0 * NQKV + 2048 + h * 64;
    const float* ol = X1 + (size_t)t0 * NQKV + 1024 + h * 64;
    for (int idx = tid; idx < 4096; idx += 256) {
        int r = idx >> 6, i = idx & 63;
        qf[r * LP + i] = (_Float16)qe[(size_t)r * NQKV + i];
        sf[r * LP + i] = (_Float16)stg[(size_t)r * NQKV + i];
    }
    __syncthreads();
    fx4 acc[4];
#pragma unroll
    for (int n = 0; n < 4; ++n)
#pragma unroll
        for (int jj = 0; jj < 4; ++jj)
            acc[n][jj] = ol[(size_t)(w * 16 + (lane >> 4) * 4 + jj) * NQKV + n * 16 + (lane & 15)];
    mm64_f16(qf, sf, w, lane, acc);
#pragma unroll
    for (int n = 0; n < 4; ++n)
#pragma unroll
        for (int jj = 0; jj < 4; ++jj)
            sO[(w * 16 + (lane >> 4) * 4 + jj) * 64 + n * 16 + (lane & 15)] = acc[n][jj];
    __syncthreads();
    int r = tid >> 2, qq = tid & 3;
    float ss = 0.f;
#pragma unroll
    for (int i2 = 0; i2 < 16; ++i2) { float v = sO[r * 64 + qq * 16 + i2]; ss += v * v; }
    part[r][qq] = ss;
    __syncthreads();
    float tot = part[r][0] + part[r][1] + part[r][2] + part[r][3];
    float sc = rsqrtf(tot * (1.f / 64.f) + 1e-6f);
    const float* gg = X1 + (size_t)(t0 + r) * NQKV + 3072 + h * 64;
#pragma unroll
    for (int i2 = 0; i2 < 16; ++i2) {
        int j = qq * 16 + i2;
        float on = sO[r * 64 + j] * sc * onw[j];
        float g = gg[j];
        float sg = g / (1.f + expf(-g));
        attn_bf[(size_t)(t0 + r) * 1024 + h * 64 + j] = __float2bfloat16(on * sg);
    }
}

// ---------------------------------------------------------------------------
extern "C" void kernel_launch(void* const* d_in, const int* in_sizes, int n_in,
                              void* d_out, int out_size, void* d_ws, size_t ws_size,
                              hipStream_t stream) {
    (void)in_sizes; (void)n_in; (void)out_size; (void)ws_size;
    const float* hidden     = (const float*)d_in[0];
    const float* norm1_w    = (const float*)d_in[1];
    const float* q_w        = (const float*)d_in[2];
    const float* k_w        = (const float*)d_in[3];
    const float* v_w        = (const float*)d_in[4];
    const float* g_w        = (const float*)d_in[5];
    const float* b_w        = (const float*)d_in[6];
    const float* gate_w     = (const float*)d_in[7];
    const float* o_norm_w   = (const float*)d_in[8];
    const float* o_w        = (const float*)d_in[9];
    const float* norm2_w    = (const float*)d_in[10];
    const float* mlp_gate_w = (const float*)d_in[11];
    const float* mlp_up_w   = (const float*)d_in[12];
    const float* mlp_down_w = (const float*)d_in[13];

    char* ws = (char*)d_ws;
    const size_t OFF_WT_QKVG = 0;          // fp16 weights 4224x1024 -> AcBuf (fp16, 4MB)
    const size_t OFF_WT_O    = 8650752;
    const size_t OFF_WT_GU   = 10747904;
    const size_t OFF_WT_DOWN = 27525120;
    const size_t OFF_X1      = 35913728;   // X1 f32 -> mbf bf16 (dead after phaseC)
    const size_t OFF_R1      = 70516736;   // BcBuf
    const size_t OFF_ATTN    = 79167488;   // attn_bf
    const size_t OFF_YBF     = 83361792;
    const size_t OFF_XHI     = 87556096;   // xhf -> UvWT (fp16, 8MB) -> h_buf
    const size_t OFF_ROPE    = 95944704;

    _Float16*       wt_qkvg = (_Float16*)(ws + OFF_WT_QKVG);
    __hip_bfloat16* wt_o    = (__hip_bfloat16*)(ws + OFF_WT_O);
    __hip_bfloat16* wt_gu   = (__hip_bfloat16*)(ws + OFF_WT_GU);
    __hip_bfloat16* wt_down = (__hip_bfloat16*)(ws + OFF_WT_DOWN);
    float*          X1      = (float*)(ws + OFF_X1);
    __hip_bfloat16* mbf     = (__hip_bfloat16*)(ws + OFF_X1);
    _Float16*       AcBuf   = (_Float16*)(ws + OFF_WT_QKVG);
    float*          BcBuf   = (float*)(ws + OFF_R1);
    __hip_bfloat16* attn_bf = (__hip_bfloat16*)(ws + OFF_ATTN);
    _Float16*       xhf     = (_Float16*)(ws + OFF_XHI);
    _Float16*       UvWT    = (_Float16*)(ws + OFF_XHI);
    float*          h_buf   = (float*)(ws + OFF_XHI);
    __hip_bfloat16* ybf     = (__hip_bfloat16*)(ws + OFF_YBF);
    float2*         rope_cs = (float2*)(ws + OFF_ROPE);

    dim3 tb(32, 8);
    rope_table_kernel<<<256, 256, 0, stream>>>(rope_cs);
    rmsnorm_fp16_kernel<<<2048, 256, 0, stream>>>(hidden, norm1_w, xhf);
    // batched fp16 weight transposes (q|k|v|gate|g|b), one launch
    transpose_fp16_x6_kernel<<<dim3(32, 32, 6), tb, 0, stream>>>(
        q_w, k_w, v_w, gate_w, g_w, b_w, wt_qkvg);
    transpose_bf16_kernel<<<dim3(32, 32), tb, 0, stream>>>(o_w, wt_o, 1024, 1024, 1024);
    transpose_bf16_gu_kernel<<<dim3(32, 128, 2), tb, 0, stream>>>(mlp_gate_w, mlp_up_w, wt_gu);
    transpose_bf16_kernel<<<dim3(128, 32), tb, 0, stream>>>(mlp_down_w, wt_down, 4096, 1024, 1024);
    // fused q|k|v|gate|g|b projection with RoPE+L2norm epilogue on q/k tiles
    gemm_bt_f16<<<dim3(66, 16), 256, 0, stream>>>(xhf, wt_qkvg, X1, rope_cs, 2048, 1024, NQKV);
    // chunked delta-rule scan
    phaseA1_kernel<<<512, 256, 0, stream>>>(X1, UvWT);
    phaseA2_kernel<<<512, 256, 0, stream>>>(X1, UvWT, AcBuf, BcBuf);
    phaseB_kernel<<<16, 256, 0, stream>>>(AcBuf, BcBuf, X1);
    phaseC_kernel<<<512, 256, 0, stream>>>(X1, o_norm_w, attn_bf);
    // attn out projection + residual (+hidden fused) -> h_buf
    gemm_bt_n64<false><<<dim3(16, 32), 256, 0, stream>>>(attn_bf, wt_o, h_buf, hidden, 2048, 1024, 1024);
    // ybf = rmsnorm(h_buf)
    rmsnorm_bf16_kernel<<<2048, 256, 0, stream>>>(h_buf, norm2_w, ybf);
    // fused mlp gate/up + silu*mul -> mbf, 128x64 tiles (1024 blocks, 4/CU)
    gemm_gateup<<<dim3(64, 16), 256, 0, stream>>>(ybf, wt_gu, wt_gu + 4096 * 1024, mbf, 2048, 1024);
    // down projection + residual add (fused) -> d_out (64x64 tiles, 512 blocks)
    gemm_bt_n64<false><<<dim3(16, 32), 256, 0, stream>>>(mbf, wt_down, (float*)d_out, h_buf, 2048, 1024, 4096);
}

// Round 26
// 300.789 us; speedup vs baseline: 1.0142x; 1.0142x over previous
//
#include <hip/hip_runtime.h>
#include <hip/hip_bf16.h>

// ---------------------------------------------------------------------------
// DepthDeltaNetDecoderLayer: B=1, T=2048, D=1024, H=16, DK=DV=64, FF=4096
// Round 26: revert round-25's rope-into-GEMM fusion (regressed +4.2us: the
// standalone rope pass was cheaper than modeled; the fused epilogue added
// shfl chains + divergence to the projection GEMM's critical path). This is
// the round-24 kernel exactly (300.83us, absmax 0.03125): standalone rope,
// batched transposes, residual adds fused into o-proj / down-proj epilogues.
// ---------------------------------------------------------------------------

#define T_SEQ 2048
#define D_MODEL 1024
#define NH 16
#define DK 64
#define DV 64
#define FF 4096
#define NQKV 4224   // X1: q(0) k(1024) v(2048) gate(3072) g(4096) b(4112) pad->4224
#define LP 72       // padded LDS stride (halfwords), 144B rows (16B-aligned)

typedef __bf16 bf16x8 __attribute__((ext_vector_type(8)));
typedef _Float16 fp16x8 __attribute__((ext_vector_type(8)));
typedef float  fx4    __attribute__((ext_vector_type(4)));

#if defined(__has_builtin)
#if __has_builtin(__builtin_amdgcn_global_load_lds)
#define HAVE_GLOAD_LDS 1
#endif
#endif

#ifdef HAVE_GLOAD_LDS
#define ASYNC_LDS16(dst, src)                                                   \
    __builtin_amdgcn_global_load_lds(                                           \
        (__attribute__((address_space(1))) void*)(src),                         \
        (__attribute__((address_space(3))) void*)(dst), 16, 0, 0)
#else
#define ASYNC_LDS16(dst, src) (*(int4*)(dst) = *(const int4*)(src))
#endif

// chunk swizzle within a 64B (32-halfword) tile row: involution, both sides.
__device__ __forceinline__ int swz_kk(int r, int ch) { return (ch ^ ((r >> 1) & 3)) * 8; }

// XCD-aware block remap (bijective when nwg % 8 == 0; all our grids qualify).
__device__ __forceinline__ void xcd_swizzle(int& bx, int& by) {
    int gx = gridDim.x, gy = gridDim.y;
    int id = blockIdx.y * gx + blockIdx.x;
    int cpx = (gx * gy) >> 3;
    int lin = (id & 7) * cpx + (id >> 3);
    bx = lin / gy;
    by = lin - bx * gy;
}

// ---------------------------------------------------------------- rope table
__global__ void rope_table_kernel(float2* __restrict__ cs) {
    int idx = blockIdx.x * 256 + threadIdx.x;
    int t = idx >> 5, i = idx & 31;
    float freq = (float)t * powf(10000.f, -(float)i / 32.f);
    cs[idx] = make_float2(cosf(freq), sinf(freq));
}

// --------------------------------------- row rmsnorm -> fp16
__global__ __launch_bounds__(256) void rmsnorm_fp16_kernel(
    const float* __restrict__ in, const float* __restrict__ w,
    _Float16* __restrict__ out) {
    int t = blockIdx.x;
    int d = threadIdx.x * 4;
    const float4 v = *(const float4*)(in + (size_t)t * D_MODEL + d);
    float ss = v.x * v.x + v.y * v.y + v.z * v.z + v.w * v.w;
#pragma unroll
    for (int m = 32; m; m >>= 1) ss += __shfl_xor(ss, m, 64);
    __shared__ float wsum[4];
    if ((threadIdx.x & 63) == 0) wsum[threadIdx.x >> 6] = ss;
    __syncthreads();
    float tot = wsum[0] + wsum[1] + wsum[2] + wsum[3];
    float sc = rsqrtf(tot * (1.f / 1024.f) + 1e-6f);
    const float4 wv = *(const float4*)(w + d);
    _Float16* op = out + (size_t)t * D_MODEL + d;
    op[0] = (_Float16)(v.x * sc * wv.x);
    op[1] = (_Float16)(v.y * sc * wv.y);
    op[2] = (_Float16)(v.z * sc * wv.z);
    op[3] = (_Float16)(v.w * sc * wv.w);
}

// -------------------------- row rmsnorm (f32 in) -> bf16
__global__ __launch_bounds__(256) void rmsnorm_bf16_kernel(
    const float* __restrict__ in, const float* __restrict__ w,
    __hip_bfloat16* __restrict__ out) {
    int t = blockIdx.x;
    int d = threadIdx.x * 4;
    const float4 h4 = *(const float4*)(in + (size_t)t * D_MODEL + d);
    float ss = h4.x * h4.x + h4.y * h4.y + h4.z * h4.z + h4.w * h4.w;
#pragma unroll
    for (int m = 32; m; m >>= 1) ss += __shfl_xor(ss, m, 64);
    __shared__ float wsum[4];
    if ((threadIdx.x & 63) == 0) wsum[threadIdx.x >> 6] = ss;
    __syncthreads();
    float tot = wsum[0] + wsum[1] + wsum[2] + wsum[3];
    float sc = rsqrtf(tot * (1.f / 1024.f) + 1e-6f);
    const float4 wv = *(const float4*)(w + d);
    __hip_bfloat16* op = out + (size_t)t * D_MODEL + d;
    op[0] = __float2bfloat16(h4.x * sc * wv.x);
    op[1] = __float2bfloat16(h4.y * sc * wv.y);
    op[2] = __float2bfloat16(h4.z * sc * wv.z);
    op[3] = __float2bfloat16(h4.w * sc * wv.w);
}

// ------------------- batched W (KxN f32) -> Wt (Npad x K fp16), z selects src
__global__ void transpose_fp16_x6_kernel(const float* __restrict__ q,
                                         const float* __restrict__ k,
                                         const float* __restrict__ v,
                                         const float* __restrict__ g,
                                         const float* __restrict__ gw,
                                         const float* __restrict__ bw,
                                         _Float16* __restrict__ Wt) {
    const int z = blockIdx.z;
    const float* W;
    int N, Npad;
    size_t ooff;
    switch (z) {
        case 0: W = q;  N = 1024; Npad = 1024; ooff = 0;               break;
        case 1: W = k;  N = 1024; Npad = 1024; ooff = 1024u * 1024u;   break;
        case 2: W = v;  N = 1024; Npad = 1024; ooff = 2048u * 1024u;   break;
        case 3: W = g;  N = 1024; Npad = 1024; ooff = 3072u * 1024u;   break;
        case 4: W = gw; N = 16;   Npad = 16;   ooff = 4096u * 1024u;   break;
        default: W = bw; N = 16;  Npad = 112;  ooff = 4112u * 1024u;   break;
    }
    __shared__ float tile[32][33];
    int k0 = blockIdx.x * 32, n0 = blockIdx.y * 32;
    if (n0 >= Npad) return;
    int tx = threadIdx.x, ty = threadIdx.y;   // (32,8)
#pragma unroll
    for (int i = 0; i < 32; i += 8) {
        int n = n0 + tx;
        tile[ty + i][tx] = (n < N) ? W[(size_t)(k0 + ty + i) * N + n] : 0.f;
    }
    __syncthreads();
#pragma unroll
    for (int i = 0; i < 32; i += 8) {
        int n = n0 + ty + i;
        if (n < Npad) Wt[ooff + (size_t)n * 1024 + k0 + tx] = (_Float16)tile[tx][ty + i];
    }
}

// ------------------------------------------- W (KxN f32) -> Wt (Npad x K bf16)
__global__ void transpose_bf16_kernel(const float* __restrict__ W,
                                      __hip_bfloat16* __restrict__ Wt,
                                      int K, int N, int Npad) {
    __shared__ float tile[32][33];
    int k0 = blockIdx.x * 32, n0 = blockIdx.y * 32;
    int tx = threadIdx.x, ty = threadIdx.y;   // (32,8)
#pragma unroll
    for (int i = 0; i < 32; i += 8) {
        int n = n0 + tx;
        tile[ty + i][tx] = (n < N) ? W[(size_t)(k0 + ty + i) * N + n] : 0.f;
    }
    __syncthreads();
#pragma unroll
    for (int i = 0; i < 32; i += 8) {
        int n = n0 + ty + i;
        if (n < Npad) Wt[(size_t)n * K + k0 + tx] = __float2bfloat16(tile[tx][ty + i]);
    }
}

// ---------- batched gate/up W (1024x4096 f32) -> Wt (4096 x 1024 bf16), z=0/1
__global__ void transpose_bf16_gu_kernel(const float* __restrict__ gate,
                                         const float* __restrict__ up,
                                         __hip_bfloat16* __restrict__ Wt) {
    const float* W = blockIdx.z ? up : gate;
    __hip_bfloat16* out = Wt + (size_t)blockIdx.z * 4096u * 1024u;
    __shared__ float tile[32][33];
    int k0 = blockIdx.x * 32, n0 = blockIdx.y * 32;
    int tx = threadIdx.x, ty = threadIdx.y;   // (32,8)
#pragma unroll
    for (int i = 0; i < 32; i += 8)
        tile[ty + i][tx] = W[(size_t)(k0 + ty + i) * 4096 + n0 + tx];
    __syncthreads();
#pragma unroll
    for (int i = 0; i < 32; i += 8)
        out[(size_t)(n0 + ty + i) * 1024 + k0 + tx] = __float2bfloat16(tile[tx][ty + i]);
}

// --------------------- fp16 single-product GEMM, 128x64 tile, f32 out (ldc)
__global__ __launch_bounds__(256) void gemm_bt_f16(
    const _Float16* __restrict__ A, const _Float16* __restrict__ Bt,
    float* __restrict__ Cout, int M, int K, int ldc) {
    __shared__ short sA[2][128 * 32];
    __shared__ short sB[2][64 * 32];
    const int tid = threadIdx.x;
    const int w = tid >> 6, lane = tid & 63;
    int bx, by;
    xcd_swizzle(bx, by);
    const int bn0 = bx * 64, bm0 = by * 128;
    const int ko = ((lane >> 4) ^ (((lane & 15) >> 1) & 3)) * 8;

    fx4 acc[2][4];
#pragma unroll
    for (int m = 0; m < 2; ++m)
#pragma unroll
        for (int n = 0; n < 4; ++n) acc[m][n] = {0.f, 0.f, 0.f, 0.f};

#pragma unroll
    for (int i = 0; i < 2; ++i) {
        int c = i * 256 + tid;
        int r = c >> 2, kk = swz_kk(r, c & 3);
        ASYNC_LDS16(&sA[0][c * 8], A + (size_t)(bm0 + r) * K + kk);
    }
    {
        int r = tid >> 2, kk = swz_kk(r, tid & 3);
        ASYNC_LDS16(&sB[0][tid * 8], Bt + (size_t)(bn0 + r) * K + kk);
    }
    __syncthreads();

    const int NT = K >> 5;
    int cur = 0;
    for (int t = 0; t < NT; ++t) {
        if (t + 1 < NT) {
            int k0 = (t + 1) << 5;
#pragma unroll
            for (int i = 0; i < 2; ++i) {
                int c = i * 256 + tid;
                int r = c >> 2, kk = swz_kk(r, c & 3);
                ASYNC_LDS16(&sA[cur ^ 1][c * 8], A + (size_t)(bm0 + r) * K + k0 + kk);
            }
            int r = tid >> 2, kk = swz_kk(r, tid & 3);
            ASYNC_LDS16(&sB[cur ^ 1][tid * 8], Bt + (size_t)(bn0 + r) * K + k0 + kk);
        }
        fp16x8 af[2], bfv[4];
#pragma unroll
        for (int m = 0; m < 2; ++m)
            af[m] = *(const fp16x8*)(&sA[cur][(w * 32 + m * 16 + (lane & 15)) * 32 + ko]);
#pragma unroll
        for (int n = 0; n < 4; ++n)
            bfv[n] = *(const fp16x8*)(&sB[cur][(n * 16 + (lane & 15)) * 32 + ko]);
#pragma unroll
        for (int m = 0; m < 2; ++m)
#pragma unroll
            for (int n = 0; n < 4; ++n)
                acc[m][n] = __builtin_amdgcn_mfma_f32_16x16x32_f16(af[m], bfv[n], acc[m][n], 0, 0, 0);
        __syncthreads();
        cur ^= 1;
    }
#pragma unroll
    for (int m = 0; m < 2; ++m) {
        int row = bm0 + w * 32 + m * 16 + (lane >> 4) * 4;
#pragma unroll
        for (int n = 0; n < 4; ++n) {
            int col = bn0 + n * 16 + (lane & 15);
#pragma unroll
            for (int j = 0; j < 4; ++j)
                Cout[(size_t)(row + j) * ldc + col] = acc[m][n][j];
        }
    }
}

// ------------------- fused gate/up GEMM + silu·mul epilogue, 128x64 tile
__global__ __launch_bounds__(256) void gemm_gateup(
    const __hip_bfloat16* __restrict__ A, const __hip_bfloat16* __restrict__ Btg,
    const __hip_bfloat16* __restrict__ Btu, __hip_bfloat16* __restrict__ Mout,
    int M, int K) {
    __shared__ short sA[2][128 * 32];
    __shared__ short sBg[2][64 * 32];
    __shared__ short sBu[2][64 * 32];
    const int tid = threadIdx.x;
    const int w = tid >> 6, lane = tid & 63;
    int bx, by;
    xcd_swizzle(bx, by);
    const int bn0 = bx * 64, bm0 = by * 128;
    const int ko = ((lane >> 4) ^ (((lane & 15) >> 1) & 3)) * 8;

    fx4 accg[2][4], accu[2][4];
#pragma unroll
    for (int m = 0; m < 2; ++m)
#pragma unroll
        for (int n = 0; n < 4; ++n) {
            accg[m][n] = {0.f, 0.f, 0.f, 0.f};
            accu[m][n] = {0.f, 0.f, 0.f, 0.f};
        }

#pragma unroll
    for (int i = 0; i < 2; ++i) {
        int c = i * 256 + tid;
        int r = c >> 2, kk = swz_kk(r, c & 3);
        ASYNC_LDS16(&sA[0][c * 8], A + (size_t)(bm0 + r) * K + kk);
    }
    {
        int r = tid >> 2, kk = swz_kk(r, tid & 3);
        ASYNC_LDS16(&sBg[0][tid * 8], Btg + (size_t)(bn0 + r) * K + kk);
        ASYNC_LDS16(&sBu[0][tid * 8], Btu + (size_t)(bn0 + r) * K + kk);
    }
    __syncthreads();

    const int NT = K >> 5;
    int cur = 0;
    for (int t = 0; t < NT; ++t) {
        if (t + 1 < NT) {
            int k0 = (t + 1) << 5;
#pragma unroll
            for (int i = 0; i < 2; ++i) {
                int c = i * 256 + tid;
                int r = c >> 2, kk = swz_kk(r, c & 3);
                ASYNC_LDS16(&sA[cur ^ 1][c * 8], A + (size_t)(bm0 + r) * K + k0 + kk);
            }
            int r = tid >> 2, kk = swz_kk(r, tid & 3);
            ASYNC_LDS16(&sBg[cur ^ 1][tid * 8], Btg + (size_t)(bn0 + r) * K + k0 + kk);
            ASYNC_LDS16(&sBu[cur ^ 1][tid * 8], Btu + (size_t)(bn0 + r) * K + k0 + kk);
        }
        bf16x8 af[2], bg[4], bu[4];
#pragma unroll
        for (int m = 0; m < 2; ++m)
            af[m] = *(const bf16x8*)(&sA[cur][(w * 32 + m * 16 + (lane & 15)) * 32 + ko]);
#pragma unroll
        for (int n = 0; n < 4; ++n) {
            int off = (n * 16 + (lane & 15)) * 32 + ko;
            bg[n] = *(const bf16x8*)(&sBg[cur][off]);
            bu[n] = *(const bf16x8*)(&sBu[cur][off]);
        }
#pragma unroll
        for (int m = 0; m < 2; ++m)
#pragma unroll
            for (int n = 0; n < 4; ++n) {
                accg[m][n] = __builtin_amdgcn_mfma_f32_16x16x32_bf16(af[m], bg[n], accg[m][n], 0, 0, 0);
                accu[m][n] = __builtin_amdgcn_mfma_f32_16x16x32_bf16(af[m], bu[n], accu[m][n], 0, 0, 0);
            }
        __syncthreads();
        cur ^= 1;
    }
#pragma unroll
    for (int m = 0; m < 2; ++m) {
        int row = bm0 + w * 32 + m * 16 + (lane >> 4) * 4;
#pragma unroll
        for (int n = 0; n < 4; ++n) {
            int col = bn0 + n * 16 + (lane & 15);
#pragma unroll
            for (int j = 0; j < 4; ++j) {
                float g = accg[m][n][j];
                float u = accu[m][n][j];
                float sg = g / (1.f + expf(-g));
                Mout[(size_t)(row + j) * 4096 + col] = __float2bfloat16(u * sg);
            }
        }
    }
}

// ----------------------------------------- GEMM, 64x64 tile (small-N shapes)
template <bool OUT_BF16>
__global__ __launch_bounds__(256, 8) void gemm_bt_n64(
    const __hip_bfloat16* __restrict__ A, const __hip_bfloat16* __restrict__ Bt,
    void* __restrict__ Cout, const float* __restrict__ Add, int M, int N, int K) {
    __shared__ short sA[2][64 * 32];
    __shared__ short sB[2][64 * 32];
    const int tid = threadIdx.x;
    const int w = tid >> 6, lane = tid & 63;
    int bx, by;
    xcd_swizzle(bx, by);
    const int bn0 = bx * 64, bm0 = by * 64;
    const int ko = ((lane >> 4) ^ (((lane & 15) >> 1) & 3)) * 8;
    const int rs = tid >> 2, cs = tid & 3;

    fx4 acc[4];
#pragma unroll
    for (int n = 0; n < 4; ++n) acc[n] = {0.f, 0.f, 0.f, 0.f};

    {
        int kk = swz_kk(rs, cs);
        ASYNC_LDS16(&sA[0][tid * 8], A + (size_t)(bm0 + rs) * K + kk);
        ASYNC_LDS16(&sB[0][tid * 8], Bt + (size_t)(bn0 + rs) * K + kk);
    }
    __syncthreads();

    const int NT = K >> 5;
    int cur = 0;
    for (int t = 0; t < NT; ++t) {
        if (t + 1 < NT) {
            int k0 = (t + 1) << 5;
            int kk = swz_kk(rs, cs);
            ASYNC_LDS16(&sA[cur ^ 1][tid * 8], A + (size_t)(bm0 + rs) * K + k0 + kk);
            ASYNC_LDS16(&sB[cur ^ 1][tid * 8], Bt + (size_t)(bn0 + rs) * K + k0 + kk);
        }
        bf16x8 af = *(const bf16x8*)(&sA[cur][(w * 16 + (lane & 15)) * 32 + ko]);
#pragma unroll
        for (int n = 0; n < 4; ++n) {
            bf16x8 bf = *(const bf16x8*)(&sB[cur][(n * 16 + (lane & 15)) * 32 + ko]);
            acc[n] = __builtin_amdgcn_mfma_f32_16x16x32_bf16(af, bf, acc[n], 0, 0, 0);
        }
        __syncthreads();
        cur ^= 1;
    }
    {
        int row = bm0 + w * 16 + (lane >> 4) * 4;
#pragma unroll
        for (int n = 0; n < 4; ++n) {
            int col = bn0 + n * 16 + (lane & 15);
#pragma unroll
            for (int j = 0; j < 4; ++j) {
                float val = acc[n][j];
                if (Add) val += Add[(size_t)(row + j) * N + col];
                if (OUT_BF16)
                    ((__hip_bfloat16*)Cout)[(size_t)(row + j) * N + col] = __float2bfloat16(val);
                else
                    ((float*)Cout)[(size_t)(row + j) * N + col] = val;
            }
        }
    }
}

// --------------------------------------------- RoPE + L2-normalize q,k in place
__global__ __launch_bounds__(256) void rope_kernel(float* __restrict__ X1,
                                                   const float2* __restrict__ cs) {
    int w = threadIdx.x >> 6, lane = threadIdx.x & 63;
    int p = blockIdx.x * 4 + w;
    int t = p >> 4, h = p & 15;
    float2 c = cs[t * 32 + (lane & 31)];
#pragma unroll
    for (int which = 0; which < 2; ++which) {
        float* base = X1 + (size_t)t * NQKV + which * 1024 + h * 64;
        float x = base[lane];
        float xo = __shfl(x, lane ^ 32, 64);
        float r = (lane < 32) ? -xo : xo;
        float y = x * c.x + r * c.y;
        float ss = y * y;
#pragma unroll
        for (int m = 32; m; m >>= 1) ss += __shfl_xor(ss, m, 64);
        base[lane] = y * rsqrtf(ss + 1e-12f);
    }
}

// ===================== chunked delta-rule: shared helpers =====================
// single-product fp16 64x64x64 matmul: C[ar][br] += sum_k A[ar][k] B[br][k]
__device__ __forceinline__ void mm64_f16(const _Float16* A, const _Float16* B,
                                         int w, int lane, fx4 acc[4]) {
#pragma unroll
    for (int k0 = 0; k0 < 64; k0 += 32) {
        int ao = (w * 16 + (lane & 15)) * LP + k0 + ((lane >> 4) * 8);
        fp16x8 a = *(const fp16x8*)(A + ao);
#pragma unroll
        for (int n = 0; n < 4; ++n) {
            int bo = (n * 16 + (lane & 15)) * LP + k0 + ((lane >> 4) * 8);
            fp16x8 b = *(const fp16x8*)(B + bo);
            acc[n] = __builtin_amdgcn_mfma_f32_16x16x32_f16(a, b, acc[n], 0, 0, 0);
        }
    }
}

// ------------------------------------------------ phase A1 (blocked solve, v3)
__global__ __launch_bounds__(256) void phaseA1_kernel(const float* __restrict__ X1,
                                                      _Float16* __restrict__ UvWT) {
    const int h = blockIdx.x & 15, c = blockIdx.x >> 4;
    const int tid = threadIdx.x, w = tid >> 6, lane = tid & 63;
    const int t0 = c * 64;

    __shared__ __align__(16) float XT[128 * 66];   // overlay: first 9216B = K staging (fp16)
    _Float16* b1f = (_Float16*)XT;
    __shared__ float sMd[4][16 * 17];
    __shared__ _Float16 mbf[6][512];
    __shared__ float sLa[64], sB[64], sL[65], sGp[64];

    const float* k_g = X1 + (size_t)t0 * NQKV + 1024 + h * 64;
    const float* v_g = X1 + (size_t)t0 * NQKV + 2048 + h * 64;

    if (tid < 64) {
        float ga = X1[(size_t)(t0 + tid) * NQKV + 4096 + h];
        float gb = X1[(size_t)(t0 + tid) * NQKV + 4112 + h];
        float z = -ga;
        sLa[tid] = -(fmaxf(z, 0.f) + log1pf(expf(-fabsf(z))));
        sB[tid] = 1.f / (1.f + expf(-gb));
    }
    __syncthreads();
    if (tid < 64) {
        float v = sLa[tid];
#pragma unroll
        for (int off = 1; off < 64; off <<= 1) {
            float u = __shfl_up(v, off, 64);
            if (tid >= off) v += u;
        }
        sL[tid + 1] = v;
        if (tid == 0) sL[0] = 0.f;
    }
    __syncthreads();
    if (tid < 64) sGp[tid] = expf(sL[tid]);
    for (int idx = tid; idx < 3072; idx += 256) ((_Float16*)mbf)[idx] = (_Float16)0.f;
    for (int idx = tid; idx < 4096; idx += 256) {
        int r = idx >> 6, cc = idx & 63;
        b1f[r * LP + cc] = (_Float16)k_g[(size_t)r * NQKV + cc];
    }
    __syncthreads();

    {
        const int r0 = w * 16;
        fx4 acc[4];
#pragma unroll
        for (int n = 0; n < 4; ++n) acc[n] = {0.f, 0.f, 0.f, 0.f};
#pragma unroll
        for (int k0 = 0; k0 < 64; k0 += 32) {
            int ao = (r0 + (lane & 15)) * LP + k0 + ((lane >> 4) * 8);
            fp16x8 a = *(const fp16x8*)(b1f + ao);
#pragma unroll
            for (int n = 0; n < 4; ++n) {
                int bo = (n * 16 + (lane & 15)) * LP + k0 + ((lane >> 4) * 8);
                fp16x8 b = *(const fp16x8*)(b1f + bo);
                acc[n] = __builtin_amdgcn_mfma_f32_16x16x32_f16(a, b, acc[n], 0, 0, 0);
            }
        }
#pragma unroll
        for (int n = 0; n < 4; ++n)
#pragma unroll
            for (int jj = 0; jj < 4; ++jj) {
                int t = r0 + (lane >> 4) * 4 + jj, s = n * 16 + (lane & 15);
                if (s < t) {
                    float mv = sB[t] * expf(sL[t] - sL[s + 1]) * acc[n][jj];
                    int J = s >> 4, tl = t - r0, sl = s & 15;
                    if (J == w) {
                        sMd[w][tl * 17 + sl] = mv;
                    } else {
                        int blk = ((w * (w - 1)) >> 1) + J;
                        mbf[blk][tl * 32 + sl] = (_Float16)mv;
                    }
                }
            }
    }
    __syncthreads();

#pragma unroll 1
    for (int I = 0; I < 4; ++I) {
        if (I > 0) {
            fx4 acc2[2];
            acc2[0] = {0.f, 0.f, 0.f, 0.f};
            acc2[1] = {0.f, 0.f, 0.f, 0.f};
#pragma unroll
            for (int g = 0; g < 2; ++g) {
                const int jb = (w * 2 + g) * 16;
                for (int J = 0; J < I; ++J) {
                    int blk = ((I * (I - 1)) >> 1) + J;
                    fp16x8 a = *(const fp16x8*)((const _Float16*)&mbf[blk][0] +
                                                (lane & 15) * 32 + (lane >> 4) * 8);
                    fp16x8 b;
                    int kabs = J * 16 + ((lane >> 4) * 8);
                    if (kabs < I * 16) {
                        const float* xp = &XT[(jb + (lane & 15)) * 66 + kabs];
#pragma unroll
                        for (int e = 0; e < 8; ++e) b[e] = (_Float16)xp[e];
                    } else {
#pragma unroll
                        for (int e = 0; e < 8; ++e) b[e] = (_Float16)0.f;
                    }
                    acc2[g] = __builtin_amdgcn_mfma_f32_16x16x32_f16(a, b, acc2[g], 0, 0, 0);
                }
            }
#pragma unroll
            for (int g = 0; g < 2; ++g) {
                const int jb = (w * 2 + g) * 16;
#pragma unroll
                for (int jj = 0; jj < 4; ++jj) {
                    int j = jb + (lane & 15);
                    int t = I * 16 + (lane >> 4) * 4 + jj;
                    XT[j * 66 + t] = acc2[g][jj];
                }
            }
        }
        __syncthreads();
        if (tid < 128) {
            const int j = tid;
            float xs[16];
#pragma unroll
            for (int tl = 0; tl < 16; ++tl) {
                const int t = I * 16 + tl;
                float base = (j < 64) ? v_g[(size_t)t * NQKV + j]
                                      : k_g[(size_t)t * NQKV + (j - 64)] * sGp[t];
                float r = sB[t] * base;
                if (I > 0) r -= XT[j * 66 + t];
#pragma unroll
                for (int sl = 0; sl < tl; ++sl)
                    r = fmaf(-sMd[I][tl * 17 + sl], xs[sl], r);
                xs[tl] = r;
                XT[j * 66 + t] = r;
            }
        }
        __syncthreads();
    }

    size_t obase = (size_t)(h * 32 + c) * 8192;
    for (int idx = tid; idx < 8192; idx += 256) {
        int t = idx >> 7, j = idx & 127;
        UvWT[obase + idx] = (_Float16)XT[j * 66 + t];
    }
}

// ------------------------------------------------ phase A2 (matmuls, fp16)
__global__ __launch_bounds__(256) void phaseA2_kernel(float* __restrict__ X1,
                                                      const _Float16* __restrict__ UvWT,
                                                      _Float16* __restrict__ AcBuf,
                                                      float* __restrict__ BcBuf) {
    const int h = blockIdx.x & 15, c = blockIdx.x >> 4;
    const int tid = threadIdx.x, w = tid >> 6, lane = tid & 63;
    const int t0 = c * 64;

    __shared__ _Float16 b1f[64 * LP], b2f[64 * LP], b3f[64 * LP], b4f[64 * LP];
    __shared__ float sLa[64], sL[65], sGp[64], sRc[64];

    const float* q_g = X1 + (size_t)t0 * NQKV + h * 64;
    const float* k_g = q_g + 1024;

    if (tid < 64) {
        float ga = X1[(size_t)(t0 + tid) * NQKV + 4096 + h];
        float z = -ga;
        sLa[tid] = -(fmaxf(z, 0.f) + log1pf(expf(-fabsf(z))));
    }
    __syncthreads();
    if (tid < 64) {
        float v = sLa[tid];
#pragma unroll
        for (int off = 1; off < 64; off <<= 1) {
            float u = __shfl_up(v, off, 64);
            if (tid >= off) v += u;
        }
        sL[tid + 1] = v;
        if (tid == 0) sL[0] = 0.f;
    }
    __syncthreads();
    if (tid < 64) {
        sGp[tid] = expf(sL[tid]);
        sRc[tid] = expf(sL[64] - sL[tid + 1]);
    }
    for (int idx = tid; idx < 4096; idx += 256) {
        int r = idx >> 6, cc = idx & 63;
        b2f[r * LP + cc] = (_Float16)q_g[(size_t)r * NQKV + cc];
        b1f[r * LP + cc] = (_Float16)k_g[(size_t)r * NQKV + cc];
    }
    const _Float16* uv = UvWT + (size_t)(h * 32 + c) * 8192;
    for (int idx = tid; idx < 8192; idx += 256) {
        int t = idx >> 7, row = idx & 127;
        _Float16* d = (row < 64) ? b3f : b4f;
        d[(row & 63) * LP + t] = uv[idx];
    }
    __syncthreads();

    fx4 pacc[4];
#pragma unroll
    for (int n = 0; n < 4; ++n) pacc[n] = {0.f, 0.f, 0.f, 0.f};
    mm64_f16(b2f, b1f, w, lane, pacc);
    __syncthreads();
#pragma unroll
    for (int n = 0; n < 4; ++n)
#pragma unroll
        for (int jj = 0; jj < 4; ++jj) {
            int t = w * 16 + (lane >> 4) * 4 + jj, s = n * 16 + (lane & 15);
            float pv = (s < t) ? expf(sL[t] - sL[s + 1]) * pacc[n][jj] : 0.f;
            b2f[t * LP + s] = (_Float16)pv;
        }
    __syncthreads();

    {
        fx4 acc[4];
#pragma unroll
        for (int n = 0; n < 4; ++n) acc[n] = {0.f, 0.f, 0.f, 0.f};
        mm64_f16(b2f, b3f, w, lane, acc);
        float* og = X1 + (size_t)t0 * NQKV + 1024 + h * 64;
#pragma unroll
        for (int n = 0; n < 4; ++n)
#pragma unroll
            for (int jj = 0; jj < 4; ++jj) {
                int t = w * 16 + (lane >> 4) * 4 + jj, s = n * 16 + (lane & 15);
                og[(size_t)t * NQKV + s] = acc[n][jj];
            }
    }
    {
        fx4 acc[4];
#pragma unroll
        for (int n = 0; n < 4; ++n) acc[n] = {0.f, 0.f, 0.f, 0.f};
        mm64_f16(b2f, b4f, w, lane, acc);
        float* qg = X1 + (size_t)t0 * NQKV + h * 64;
#pragma unroll
        for (int n = 0; n < 4; ++n)
#pragma unroll
            for (int jj = 0; jj < 4; ++jj) {
                int t = w * 16 + (lane >> 4) * 4 + jj, s = n * 16 + (lane & 15);
                float qv = qg[(size_t)t * NQKV + s];
                qg[(size_t)t * NQKV + s] = sGp[t] * qv - acc[n][jj];
            }
    }
    __syncthreads();
    for (int idx = tid; idx < 4096; idx += 256) {
        int s = idx >> 6, i = idx & 63;
        float kv = (float)b1f[s * LP + i];
        b2f[i * LP + s] = (_Float16)(sRc[s] * kv);
    }
    __syncthreads();

    {
        fx4 acc[4];
#pragma unroll
        for (int n = 0; n < 4; ++n) acc[n] = {0.f, 0.f, 0.f, 0.f};
        mm64_f16(b2f, b4f, w, lane, acc);
        float gend = expf(sL[64]);
        size_t abase = (size_t)(h * 32 + c) * 4096;
#pragma unroll
        for (int n = 0; n < 4; ++n)
#pragma unroll
            for (int jj = 0; jj < 4; ++jj) {
                int i = w * 16 + (lane >> 4) * 4 + jj, jd = n * 16 + (lane & 15);
                float av = ((i == jd) ? gend : 0.f) - acc[n][jj];
                AcBuf[abase + i * 64 + jd] = (_Float16)av;
            }
    }
    {
        fx4 acc[4];
#pragma unroll
        for (int n = 0; n < 4; ++n) acc[n] = {0.f, 0.f, 0.f, 0.f};
        mm64_f16(b3f, b2f, w, lane, acc);
        size_t bbase = (size_t)(h * 32 + c) * 4096;
#pragma unroll
        for (int n = 0; n < 4; ++n)
#pragma unroll
            for (int jj = 0; jj < 4; ++jj) {
                int jv = w * 16 + (lane >> 4) * 4 + jj, i = n * 16 + (lane & 15);
                BcBuf[bbase + jv * 64 + i] = acc[n][jj];
            }
    }
}

// --------------------------------------------------- phase B (state recurrence)
__global__ __launch_bounds__(256) void phaseB_kernel(const _Float16* __restrict__ AcBuf,
                                                     const float* __restrict__ BcBuf,
                                                     float* __restrict__ X1) {
    const int h = blockIdx.x;
    const int tid = threadIdx.x, w = tid >> 6, lane = tid & 63;
    const int lr = (lane >> 4) * 4;
    const int lc = lane & 15;
    __shared__ _Float16 sAc[2][4096];
    __shared__ float sST[64 * 68];

    const size_t hc0 = (size_t)h * 32;
    {
        const char* src = (const char*)AcBuf + hc0 * 8192;
        char* dst = (char*)&sAc[0][0];
        int off = tid * 16;
        ASYNC_LDS16(dst + off, src + off);
        ASYNC_LDS16(dst + off + 4096, src + off + 4096);
    }
    fx4 acc[4];
#pragma unroll
    for (int n = 0; n < 4; ++n) acc[n] = {0.f, 0.f, 0.f, 0.f};
    float bcur[16];
    {
        const float* bg = BcBuf + hc0 * 4096;
#pragma unroll
        for (int n = 0; n < 4; ++n)
#pragma unroll
            for (int jj = 0; jj < 4; ++jj)
                bcur[n * 4 + jj] = bg[(w * 16 + lr + jj) * 64 + n * 16 + lc];
    }

#pragma unroll 1
    for (int c = 0; c < 32; ++c) {
        __syncthreads();
        {
            int cn = (c < 31) ? c + 1 : 31;
            const char* src = (const char*)AcBuf + (hc0 + cn) * 8192;
            char* dst = (char*)&sAc[(c + 1) & 1][0];
            int off = tid * 16;
            ASYNC_LDS16(dst + off, src + off);
            ASYNC_LDS16(dst + off + 4096, src + off + 4096);
        }
        float bnext[16];
        {
            int cn = (c < 31) ? c + 1 : 31;
            const float* bg = BcBuf + (hc0 + cn) * 4096;
#pragma unroll
            for (int n = 0; n < 4; ++n)
#pragma unroll
                for (int jj = 0; jj < 4; ++jj)
                    bnext[n * 4 + jj] = bg[(w * 16 + lr + jj) * 64 + n * 16 + lc];
        }
        float* stg = X1 + (size_t)(c * 64) * NQKV + 2048 + h * 64;
#pragma unroll
        for (int n = 0; n < 4; ++n)
#pragma unroll
            for (int jj = 0; jj < 4; ++jj) {
                int r = w * 16 + lr + jj, i = n * 16 + lc;
                stg[(size_t)r * NQKV + i] = acc[n][jj];
                sST[r * 68 + i] = acc[n][jj];
            }
        const _Float16* bufc = &sAc[c & 1][0];
        fx4 nacc[4];
#pragma unroll
        for (int n = 0; n < 4; ++n)
            nacc[n] = {bcur[n * 4 + 0], bcur[n * 4 + 1], bcur[n * 4 + 2], bcur[n * 4 + 3]};
#pragma unroll
        for (int k0 = 0; k0 < 2; ++k0) {
            const float* ap = sST + (w * 16 + lc) * 68 + k0 * 32 + (lane >> 4) * 8;
            float4 f0 = *(const float4*)ap;
            float4 f1 = *(const float4*)(ap + 4);
            float fv[8] = {f0.x, f0.y, f0.z, f0.w, f1.x, f1.y, f1.z, f1.w};
            fp16x8 af_;
#pragma unroll
            for (int e = 0; e < 8; ++e) af_[e] = (_Float16)fv[e];
#pragma unroll
            for (int n = 0; n < 4; ++n) {
                int ro = (n * 16 + lc) * 64 + k0 * 32 + (lane >> 4) * 8;
                fp16x8 b_ = *(const fp16x8*)(bufc + ro);
                nacc[n] = __builtin_amdgcn_mfma_f32_16x16x32_f16(af_, b_, nacc[n], 0, 0, 0);
            }
        }
#pragma unroll
        for (int n = 0; n < 4; ++n) acc[n] = nacc[n];
#pragma unroll
        for (int e = 0; e < 16; ++e) bcur[e] = bnext[e];
    }
}

// --------------------------------------------- phase C (outputs + epilogue)
__global__ __launch_bounds__(256) void phaseC_kernel(const float* __restrict__ X1,
                                                     const float* __restrict__ onw,
                                                     __hip_bfloat16* __restrict__ attn_bf) {
    const int h = blockIdx.x & 15, c = blockIdx.x >> 4;
    const int tid = threadIdx.x, w = tid >> 6, lane = tid & 63;
    const int t0 = c * 64;
    __shared__ _Float16 qf[64 * LP], sf[64 * LP];
    __shared__ float sO[4096];
    __shared__ float part[64][4];
    const float* qe = X1 + (size_t)t0 * NQKV + h * 64;
    const float* stg = X1 + (size_t)t0 * NQKV + 2048 + h * 64;
    const float* ol = X1 + (size_t)t0 * NQKV + 1024 + h * 64;
    for (int idx = tid; idx < 4096; idx += 256) {
        int r = idx >> 6, i = idx & 63;
        qf[r * LP + i] = (_Float16)qe[(size_t)r * NQKV + i];
        sf[r * LP + i] = (_Float16)stg[(size_t)r * NQKV + i];
    }
    __syncthreads();
    fx4 acc[4];
#pragma unroll
    for (int n = 0; n < 4; ++n)
#pragma unroll
        for (int jj = 0; jj < 4; ++jj)
            acc[n][jj] = ol[(size_t)(w * 16 + (lane >> 4) * 4 + jj) * NQKV + n * 16 + (lane & 15)];
    mm64_f16(qf, sf, w, lane, acc);
#pragma unroll
    for (int n = 0; n < 4; ++n)
#pragma unroll
        for (int jj = 0; jj < 4; ++jj)
            sO[(w * 16 + (lane >> 4) * 4 + jj) * 64 + n * 16 + (lane & 15)] = acc[n][jj];
    __syncthreads();
    int r = tid >> 2, qq = tid & 3;
    float ss = 0.f;
#pragma unroll
    for (int i2 = 0; i2 < 16; ++i2) { float v = sO[r * 64 + qq * 16 + i2]; ss += v * v; }
    part[r][qq] = ss;
    __syncthreads();
    float tot = part[r][0] + part[r][1] + part[r][2] + part[r][3];
    float sc = rsqrtf(tot * (1.f / 64.f) + 1e-6f);
    const float* gg = X1 + (size_t)(t0 + r) * NQKV + 3072 + h * 64;
#pragma unroll
    for (int i2 = 0; i2 < 16; ++i2) {
        int j = qq * 16 + i2;
        float on = sO[r * 64 + j] * sc * onw[j];
        float g = gg[j];
        float sg = g / (1.f + expf(-g));
        attn_bf[(size_t)(t0 + r) * 1024 + h * 64 + j] = __float2bfloat16(on * sg);
    }
}

// ---------------------------------------------------------------------------
extern "C" void kernel_launch(void* const* d_in, const int* in_sizes, int n_in,
                              void* d_out, int out_size, void* d_ws, size_t ws_size,
                              hipStream_t stream) {
    (void)in_sizes; (void)n_in; (void)out_size; (void)ws_size;
    const float* hidden     = (const float*)d_in[0];
    const float* norm1_w    = (const float*)d_in[1];
    const float* q_w        = (const float*)d_in[2];
    const float* k_w        = (const float*)d_in[3];
    const float* v_w        = (const float*)d_in[4];
    const float* g_w        = (const float*)d_in[5];
    const float* b_w        = (const float*)d_in[6];
    const float* gate_w     = (const float*)d_in[7];
    const float* o_norm_w   = (const float*)d_in[8];
    const float* o_w        = (const float*)d_in[9];
    const float* norm2_w    = (const float*)d_in[10];
    const float* mlp_gate_w = (const float*)d_in[11];
    const float* mlp_up_w   = (const float*)d_in[12];
    const float* mlp_down_w = (const float*)d_in[13];

    char* ws = (char*)d_ws;
    const size_t OFF_WT_QKVG = 0;          // fp16 weights 4224x1024 -> AcBuf (fp16, 4MB)
    const size_t OFF_WT_O    = 8650752;
    const size_t OFF_WT_GU   = 10747904;
    const size_t OFF_WT_DOWN = 27525120;
    const size_t OFF_X1      = 35913728;   // X1 f32 -> mbf bf16 (dead after phaseC)
    const size_t OFF_R1      = 70516736;   // BcBuf
    const size_t OFF_ATTN    = 79167488;   // attn_bf
    const size_t OFF_YBF     = 83361792;
    const size_t OFF_XHI     = 87556096;   // xhf -> UvWT (fp16, 8MB) -> h_buf
    const size_t OFF_ROPE    = 95944704;

    _Float16*       wt_qkvg = (_Float16*)(ws + OFF_WT_QKVG);
    __hip_bfloat16* wt_o    = (__hip_bfloat16*)(ws + OFF_WT_O);
    __hip_bfloat16* wt_gu   = (__hip_bfloat16*)(ws + OFF_WT_GU);
    __hip_bfloat16* wt_down = (__hip_bfloat16*)(ws + OFF_WT_DOWN);
    float*          X1      = (float*)(ws + OFF_X1);
    __hip_bfloat16* mbf     = (__hip_bfloat16*)(ws + OFF_X1);
    _Float16*       AcBuf   = (_Float16*)(ws + OFF_WT_QKVG);
    float*          BcBuf   = (float*)(ws + OFF_R1);
    __hip_bfloat16* attn_bf = (__hip_bfloat16*)(ws + OFF_ATTN);
    _Float16*       xhf     = (_Float16*)(ws + OFF_XHI);
    _Float16*       UvWT    = (_Float16*)(ws + OFF_XHI);
    float*          h_buf   = (float*)(ws + OFF_XHI);
    __hip_bfloat16* ybf     = (__hip_bfloat16*)(ws + OFF_YBF);
    float2*         rope_cs = (float2*)(ws + OFF_ROPE);

    dim3 tb(32, 8);
    rope_table_kernel<<<256, 256, 0, stream>>>(rope_cs);
    rmsnorm_fp16_kernel<<<2048, 256, 0, stream>>>(hidden, norm1_w, xhf);
    // batched fp16 weight transposes (q|k|v|gate|g|b), one launch
    transpose_fp16_x6_kernel<<<dim3(32, 32, 6), tb, 0, stream>>>(
        q_w, k_w, v_w, gate_w, g_w, b_w, wt_qkvg);
    transpose_bf16_kernel<<<dim3(32, 32), tb, 0, stream>>>(o_w, wt_o, 1024, 1024, 1024);
    transpose_bf16_gu_kernel<<<dim3(32, 128, 2), tb, 0, stream>>>(mlp_gate_w, mlp_up_w, wt_gu);
    transpose_bf16_kernel<<<dim3(128, 32), tb, 0, stream>>>(mlp_down_w, wt_down, 4096, 1024, 1024);
    // fused q|k|v|gate|g|b projection (single-product fp16, 128x64 tiles)
    gemm_bt_f16<<<dim3(66, 16), 256, 0, stream>>>(xhf, wt_qkvg, X1, 2048, 1024, NQKV);
    rope_kernel<<<8192, 256, 0, stream>>>(X1, rope_cs);
    // chunked delta-rule scan
    phaseA1_kernel<<<512, 256, 0, stream>>>(X1, UvWT);
    phaseA2_kernel<<<512, 256, 0, stream>>>(X1, UvWT, AcBuf, BcBuf);
    phaseB_kernel<<<16, 256, 0, stream>>>(AcBuf, BcBuf, X1);
    phaseC_kernel<<<512, 256, 0, stream>>>(X1, o_norm_w, attn_bf);
    // attn out projection + residual (+hidden fused) -> h_buf
    gemm_bt_n64<false><<<dim3(16, 32), 256, 0, stream>>>(attn_bf, wt_o, h_buf, hidden, 2048, 1024, 1024);
    // ybf = rmsnorm(h_buf)
    rmsnorm_bf16_kernel<<<2048, 256, 0, stream>>>(h_buf, norm2_w, ybf);
    // fused mlp gate/up + silu*mul -> mbf, 128x64 tiles (1024 blocks, 4/CU)
    gemm_gateup<<<dim3(64, 16), 256, 0, stream>>>(ybf, wt_gu, wt_gu + 4096 * 1024, mbf, 2048, 1024);
    // down projection + residual add (fused) -> d_out (64x64 tiles, 512 blocks)
    gemm_bt_n64<false><<<dim3(16, 32), 256, 0, stream>>>(mbf, wt_down, (float*)d_out, h_buf, 2048, 1024, 4096);
}